// Round 13
// baseline (5608.342 us; speedup 1.0000x reference)
//
#include <hip/hip_runtime.h>
#include <hip/hip_bf16.h>

// ---------------------------------------------------------------------------
// LSTM (faithful-bug variant) on MI355X — persistent, fence-free barrier, v11.
// carry (a, b):  a = cell chain, b = hidden chain (fed into the matmul)
//   z[g] = b_prev @ Wc[g]^T + T[x_t][g]     (T = embed-part + bias, per token)
//   g=tanh(z0) i=sig(z1) f=sig(z2) o=sig(z3)
//   a_new = g*i + a_prev*f ;  b_new = tanh(a_new)*o
// output = softmax(a_final @ w_p^T + b_p)
//
// Swapped GEMM Zt[wcol][batch] = Wt[wcol][k] · h_prev[batch][k], wcol = j*4+g
// so each lane's 4 acc regs are the 4 gates of one (batch, j) pair.
// v11 (vs v10/R12, which ran 25us/step at 1 block/CU with buffer_inv nuking
// L2 every step):
//  - grid 512, tile 128 wcol x 64 batch (R7 shape), LDS 72KB -> 2 blocks/CU;
//    paired blocks come from different groups -> barrier waits overlap.
//  - H is the ONLY cross-block mutable data: H staged with aux=sc0|sc1=17
//    (L1/L2-bypass, read at coherence point) and stored write-through via
//    inline asm global_store_short sc0 sc1. Barrier = syncthreads + counter
//    atomics ONLY - no cache fences -> W stays L2-resident forever.
// ---------------------------------------------------------------------------

typedef __attribute__((ext_vector_type(8))) short bf16x8;
typedef __attribute__((ext_vector_type(4))) float f32x4;

#define GLOBAL_AS __attribute__((address_space(1)))
#define LDS_AS    __attribute__((address_space(3)))

static __device__ __forceinline__ void async_copy16(const void* g, void* l) {
    __builtin_amdgcn_global_load_lds((const GLOBAL_AS void*)g, (LDS_AS void*)l, 16, 0, 0);
}
// device-coherent (sc0|sc1 = 17): bypass L1/L2, read at coherence point
static __device__ __forceinline__ void async_copy16_dc(const void* g, void* l) {
    __builtin_amdgcn_global_load_lds((const GLOBAL_AS void*)g, (LDS_AS void*)l, 16, 0, 17);
}
static __device__ __forceinline__ void store_bf16_dc(__hip_bfloat16* p, __hip_bfloat16 v) {
    unsigned d = (unsigned)__builtin_bit_cast(unsigned short, v);
    asm volatile("global_store_short %0, %1, off sc0 sc1"
                 :: "v"(p), "v"(d) : "memory");
}
static __device__ __forceinline__ float sigm(float x) {
    return 1.f / (1.f + __expf(-x));
}
static __device__ __forceinline__ float tanh_fast(float x) {
    return 1.f - 2.f / (__expf(2.f * x) + 1.f);
}

// ---------------- prep 1: gate table T[s][j*4+g] (embed part + bias) -------
__global__ __launch_bounds__(256) void prep_table(
    const float* __restrict__ embed,                       // [128][256]
    const float* __restrict__ wg, const float* __restrict__ wi,
    const float* __restrict__ wf, const float* __restrict__ wo,
    const float* __restrict__ bg, const float* __restrict__ bi,
    const float* __restrict__ bff, const float* __restrict__ bo,
    float* __restrict__ T)                                 // [128][4096] interleaved
{
    __shared__ float e[8][256];
    const int tid = threadIdx.x;
    const int col = blockIdx.x * 256 + tid;                // 0..4095
    const int s0 = blockIdx.y * 8;
    const int j = col >> 2, g = col & 3;
    const float* w = (g == 0 ? wg : g == 1 ? wi : g == 2 ? wf : wo) + (size_t)j * 1280;
    const float bias = (g == 0 ? bg : g == 1 ? bi : g == 2 ? bff : bo)[j];
    #pragma unroll
    for (int i = 0; i < 8; ++i) e[i][tid] = embed[(s0 + i) * 256 + tid];
    __syncthreads();
    const float4* w4 = (const float4*)w;
    float acc[8];
    #pragma unroll
    for (int i = 0; i < 8; ++i) acc[i] = bias;
    for (int d = 0; d < 64; ++d) {
        const float4 wv = w4[d];
        #pragma unroll
        for (int i = 0; i < 8; ++i) {
            const float4 ev = ((const float4*)e[i])[d];
            acc[i] += ev.x * wv.x + ev.y * wv.y + ev.z * wv.z + ev.w * wv.w;
        }
    }
    #pragma unroll
    for (int i = 0; i < 8; ++i)
        T[(size_t)(s0 + i) * 4096 + col] = acc[i];
}

// ---------------- prep 2: pack recurrent weights bf16, gate-interleaved ----
__global__ __launch_bounds__(256) void pack_w(
    const float* __restrict__ wg, const float* __restrict__ wi,
    const float* __restrict__ wf, const float* __restrict__ wo,
    __hip_bfloat16* __restrict__ Wt)                       // [4096][1024]
{
    const int col = blockIdx.x;                            // wcol = j*4+g
    const int j = col >> 2, g = col & 3;
    const float* w = (g == 0 ? wg : g == 1 ? wi : g == 2 ? wf : wo)
                     + (size_t)j * 1280 + 256;             // skip embed part
    __hip_bfloat16* out = Wt + (size_t)col * 1024;
    for (int k = threadIdx.x; k < 1024; k += 256)
        out[k] = __float2bfloat16(w[k]);
}

// ---------------- persistent LSTM ------------------------------------------
// PLAIN launch, grid 512 (2 blocks/CU: 72KB LDS, <=128 VGPR, 16 waves/CU).
// wcb = bid&31 (128 wcols), grp = bid>>5 (16 groups x 64 batch rows).
// 512 threads, 8 waves in 4(wm) x 2(wn); wave tile 32 wcol x 32 batch,
// acc[2][2] of 16x16x32 (the R7-proven shape).
// LDS: 3 buffers x { Ws 128x64 bf16 16KB | Hs 64x64 8KB } = 72KB, swizzled
// 128B rows XOR(row&7) (conflict-free, R7/R12-proven).
// Inter-step sync: per-group atomic counter, NO fences (H bypasses L2).
__global__ __launch_bounds__(512, 4) void lstm_persist(
    const __hip_bfloat16* __restrict__ Wt,   // [4096][1024]
    const float* __restrict__ T,             // [128][4096] interleaved
    const int* __restrict__ X,               // [1024][128]
    __hip_bfloat16* __restrict__ BhA,        // [1024][1024] h buf 0 (zeroed)
    __hip_bfloat16* __restrict__ BhB,        // [1024][1024] h buf 1
    float* __restrict__ CSout,               // [1024][1024] final cell state
    unsigned* __restrict__ cnt)              // [16*32] group counters (zeroed)
{
    __shared__ char lds[3][24576];           // [buf]{ Ws 16KB | Hs 8KB }
    const int tid = threadIdx.x;
    const int w = tid >> 6, l = tid & 63;
    const int wm = w >> 1, wn = w & 1;
    const int wcol0 = (blockIdx.x & 31) * 128;
    const int grp = blockIdx.x >> 5;         // batch group 0..15
    const int batch0 = grp * 64;
    unsigned* mycnt = cnt + grp * 32;        // 128B-spaced counter

    int batchN[2], jM[2];
    #pragma unroll
    for (int n = 0; n < 2; ++n) batchN[n] = batch0 + wn * 32 + n * 16 + (l & 15);
    #pragma unroll
    for (int m = 0; m < 2; ++m) jM[m] = (wcol0 >> 2) + wm * 8 + m * 4 + (l >> 4);

    // cell state lives in registers for the whole recurrence
    float cs[2][2];
    #pragma unroll
    for (int m = 0; m < 2; ++m)
        #pragma unroll
        for (int n = 0; n < 2; ++n) cs[m][n] = 0.f;

    // gate-table operand for step 0
    f32x4 tv[2][2];
    #pragma unroll
    for (int n = 0; n < 2; ++n) {
        const int s = X[batchN[n] * 128 + 0];
        #pragma unroll
        for (int m = 0; m < 2; ++m)
            tv[m][n] = *(const f32x4*)&T[(size_t)s * 4096 + jM[m] * 4];
    }

    // slot s: row = s>>3, chunk = s&7 (16B chunks of the 128B row).
    // LDS dest linear in s; global SOURCE chunk is ch^(row&7); reader applies
    // the same XOR -> involution cancels (rule 21). 3 loads per STAGE
    // (2x W cached, 1x H device-coherent).
#define STAGE(K0, BUF) do {                                                    \
        _Pragma("unroll")                                                      \
        for (int i_ = 0; i_ < 2; ++i_) {                                       \
            const int sW = tid + i_ * 512;                                     \
            const int rW = sW >> 3, cW = sW & 7;                               \
            async_copy16(Wt + (size_t)(wcol0 + rW) * 1024 + (K0)               \
                             + ((cW ^ (rW & 7)) << 3),                         \
                         &lds[BUF][sW * 16]);                                  \
        }                                                                      \
        const int sH = tid;                                                    \
        const int rH = sH >> 3, cH = sH & 7;                                   \
        async_copy16_dc(Hp + (size_t)(batch0 + rH) * 1024 + (K0)               \
                            + ((cH ^ (rH & 7)) << 3),                          \
                        &lds[BUF][16384 + sH * 16]);                           \
    } while (0)

    for (int t = 0; t < 128; ++t) {
        const __hip_bfloat16* Hp = (t & 1) ? BhB : BhA;
        __hip_bfloat16*       Hn = (t & 1) ? BhA : BhB;

        // ---- prologue: stage K-tiles 0 and 1 ------------------------------
        STAGE(0, 0);
        STAGE(64, 1);

        f32x4 acc[2][2];
        const f32x4 z4 = {0.f, 0.f, 0.f, 0.f};
        #pragma unroll
        for (int m = 0; m < 2; ++m)
            #pragma unroll
            for (int n = 0; n < 2; ++n) acc[m][n] = z4;

        // ---- K loop: 16 tiles of BK=64, 3-buffer, 2-ahead, 1 barrier/tile -
        // STAGE = 3 loads; 2 stages in flight -> vmcnt(3) waits for the stage
        // issued two iterations ago (kt=15: full drain).
        #pragma unroll
        for (int kt = 0; kt < 16; ++kt) {
            if (kt == 15) asm volatile("s_waitcnt vmcnt(0)" ::: "memory");
            else          asm volatile("s_waitcnt vmcnt(3)" ::: "memory");
            __builtin_amdgcn_s_barrier();    // tile kt in LDS for ALL waves;
                                             // compute(kt-1) done -> safe to
                                             // overwrite buf[(kt+2)%3]
            if (kt < 14) STAGE((kt + 2) * 64, (kt + 2) % 3);

            const char* base = &lds[kt % 3][0];
            bf16x8 af0[2], af1[2], bfr0[2], bfr1[2];
            #pragma unroll
            for (int m = 0; m < 2; ++m) {
                const int row = wm * 32 + m * 16 + (l & 15);
                const int ch0 = (l >> 4) ^ (row & 7);
                const int ch1 = (4 + (l >> 4)) ^ (row & 7);
                af0[m] = *(const bf16x8*)(base + (row * 8 + ch0) * 16);
                af1[m] = *(const bf16x8*)(base + (row * 8 + ch1) * 16);
            }
            #pragma unroll
            for (int n = 0; n < 2; ++n) {
                const int row = wn * 32 + n * 16 + (l & 15);
                const int ch0 = (l >> 4) ^ (row & 7);
                const int ch1 = (4 + (l >> 4)) ^ (row & 7);
                bfr0[n] = *(const bf16x8*)(base + 16384 + (row * 8 + ch0) * 16);
                bfr1[n] = *(const bf16x8*)(base + 16384 + (row * 8 + ch1) * 16);
            }
            __builtin_amdgcn_s_setprio(1);
            #pragma unroll
            for (int m = 0; m < 2; ++m)
                #pragma unroll
                for (int n = 0; n < 2; ++n)
                    acc[m][n] = __builtin_amdgcn_mfma_f32_16x16x32_bf16(
                        af0[m], bfr0[n], acc[m][n], 0, 0, 0);
            #pragma unroll
            for (int m = 0; m < 2; ++m)
                #pragma unroll
                for (int n = 0; n < 2; ++n)
                    acc[m][n] = __builtin_amdgcn_mfma_f32_16x16x32_bf16(
                        af1[m], bfr1[n], acc[m][n], 0, 0, 0);
            __builtin_amdgcn_s_setprio(0);
        }

        // ---- prefetch next step's gate-table operand (read-only data) -----
        f32x4 tvn[2][2];
        if (t < 127) {
            #pragma unroll
            for (int n = 0; n < 2; ++n) {
                const int s = X[batchN[n] * 128 + t + 1];
                #pragma unroll
                for (int m = 0; m < 2; ++m)
                    tvn[m][n] = *(const f32x4*)&T[(size_t)s * 4096 + jM[m] * 4];
            }
        }

        // ---- in-register epilogue; H stored write-through (sc0 sc1) -------
        #pragma unroll
        for (int m = 0; m < 2; ++m)
            #pragma unroll
            for (int n = 0; n < 2; ++n) {
                const float z0 = acc[m][n][0] + tv[m][n][0];
                const float z1 = acc[m][n][1] + tv[m][n][1];
                const float z2 = acc[m][n][2] + tv[m][n][2];
                const float z3 = acc[m][n][3] + tv[m][n][3];
                const float gg = tanh_fast(z0);
                const float ii = sigm(z1);
                const float ff = sigm(z2);
                const float oo = sigm(z3);
                const float na = gg * ii + cs[m][n] * ff;
                cs[m][n] = na;
                store_bf16_dc(Hn + (size_t)batchN[n] * 1024 + jM[m],
                              __float2bfloat16(tanh_fast(na) * oo));
            }
        if (t < 127) {
            #pragma unroll
            for (int m = 0; m < 2; ++m)
                #pragma unroll
                for (int n = 0; n < 2; ++n) tv[m][n] = tvn[m][n];
        }

        // ---- group barrier: counter only, NO cache fences -----------------
        // H stores are write-through (drained by the implicit vmcnt(0) of
        // __syncthreads); H loads bypass L2 -> no invalidate needed.
        if (t < 127) {
            asm volatile("s_waitcnt vmcnt(0)" ::: "memory");
            __syncthreads();                 // whole block done with step t
            if (tid == 0) {
                __hip_atomic_fetch_add(mycnt, 1u, __ATOMIC_RELEASE,
                                       __HIP_MEMORY_SCOPE_AGENT);
                const unsigned tgt = 32u * (unsigned)(t + 1);
                while (__hip_atomic_load(mycnt, __ATOMIC_ACQUIRE,
                                         __HIP_MEMORY_SCOPE_AGENT) < tgt)
                    __builtin_amdgcn_s_sleep(2);
            }
            __syncthreads();                 // peers' h_prev now visible
        }
    }
#undef STAGE

    // ---- final cell state -------------------------------------------------
    #pragma unroll
    for (int m = 0; m < 2; ++m)
        #pragma unroll
        for (int n = 0; n < 2; ++n)
            CSout[(size_t)batchN[n] * 1024 + jM[m]] = cs[m][n];
}

// ---------------- final projection + softmax -------------------------------
__global__ __launch_bounds__(256) void proj_softmax(
    const float* __restrict__ A,             // [1024][1024]
    const float* __restrict__ Wp,            // [10][1024]
    const float* __restrict__ bp,            // [10]
    float* __restrict__ out)                 // [1024][10]
{
    const int row = blockIdx.x;
    const float* a = A + (size_t)row * 1024;
    float p[10];
    #pragma unroll
    for (int c = 0; c < 10; ++c) p[c] = 0.f;
    for (int k = threadIdx.x; k < 1024; k += 256) {
        const float av = a[k];
        #pragma unroll
        for (int c = 0; c < 10; ++c) p[c] += av * Wp[c * 1024 + k];
    }
    #pragma unroll
    for (int c = 0; c < 10; ++c)
        #pragma unroll
        for (int off = 32; off; off >>= 1) p[c] += __shfl_down(p[c], off);
    __shared__ float red[4][10];
    const int wv = threadIdx.x >> 6, ln = threadIdx.x & 63;
    if (ln == 0)
        for (int c = 0; c < 10; ++c) red[wv][c] = p[c];
    __syncthreads();
    if (threadIdx.x == 0) {
        float logits[10], mx = -1e30f;
        for (int c = 0; c < 10; ++c) {
            logits[c] = red[0][c] + red[1][c] + red[2][c] + red[3][c] + bp[c];
            mx = fmaxf(mx, logits[c]);
        }
        float sum = 0.f;
        for (int c = 0; c < 10; ++c) { logits[c] = __expf(logits[c] - mx); sum += logits[c]; }
        const float inv = 1.f / sum;
        for (int c = 0; c < 10; ++c) out[(size_t)row * 10 + c] = logits[c] * inv;
    }
}

// ---------------------------------------------------------------------------
extern "C" void kernel_launch(void* const* d_in, const int* in_sizes, int n_in,
                              void* d_out, int out_size, void* d_ws, size_t ws_size,
                              hipStream_t stream) {
    (void)in_sizes; (void)n_in; (void)out_size; (void)ws_size;
    const int*   x     = (const int*)d_in[0];
    const float* embed = (const float*)d_in[1];
    const float* wg    = (const float*)d_in[2];
    const float* wi    = (const float*)d_in[3];
    const float* wf    = (const float*)d_in[4];
    const float* wo    = (const float*)d_in[5];
    const float* bg    = (const float*)d_in[6];
    const float* bi    = (const float*)d_in[7];
    const float* bff   = (const float*)d_in[8];
    const float* bo    = (const float*)d_in[9];
    const float* wp    = (const float*)d_in[10];
    const float* bp    = (const float*)d_in[11];
    float* out = (float*)d_out;

    char* ws = (char*)d_ws;
    float*          T    = (float*)(ws);                        // 2 MB
    __hip_bfloat16* Wt   = (__hip_bfloat16*)(ws + (2u << 20));  // 8 MB
    __hip_bfloat16* BhA  = (__hip_bfloat16*)(ws + (10u << 20)); // 2 MB
    __hip_bfloat16* BhB  = (__hip_bfloat16*)(ws + (12u << 20)); // 2 MB
    float*          CSo  = (float*)(ws + (14u << 20));          // 4 MB
    unsigned*       cnt  = (unsigned*)(ws + (18u << 20));       // 2 KB

    prep_table<<<dim3(16, 16), 256, 0, stream>>>(embed, wg, wi, wf, wo, bg, bi, bff, bo, T);
    pack_w<<<4096, 256, 0, stream>>>(wg, wi, wf, wo, Wt);
    hipMemsetAsync(BhA, 0, (size_t)1024 * 1024 * sizeof(__hip_bfloat16), stream);
    hipMemsetAsync(cnt, 0, 16 * 32 * sizeof(unsigned), stream);

    lstm_persist<<<512, 512, 0, stream>>>(Wt, T, x, BhA, BhB, CSo, cnt);

    proj_softmax<<<1024, 256, 0, stream>>>(CSo, wp, bp, out);
}

// Round 14
// 2235.704 us; speedup vs baseline: 2.5085x; 2.5085x over previous
//
#include <hip/hip_runtime.h>
#include <hip/hip_bf16.h>

// ---------------------------------------------------------------------------
// LSTM (faithful-bug variant) on MI355X — per-step launch, fat batch tile v12.
// carry (a, b):  a = cell chain, b = hidden chain (fed into the matmul)
//   z[g] = b_prev @ Wc[g]^T + T[x_t][g]     (T = embed-part + bias, per token)
//   g=tanh(z0) i=sig(z1) f=sig(z2) o=sig(z3)
//   a_new = g*i + a_prev*f ;  b_new = tanh(a_new)*o
// output = softmax(a_final @ w_p^T + b_p)
//
// Swapped GEMM Zt[wcol][batch] = Wt[wcol][k] · h_prev[batch][k], wcol = j*4+g
// so each lane's 4 acc regs are the 4 gates of one (batch, j) pair.
// v12: R4-proven launcher schedule (BK=64 double-buffer, counted vmcnt,
// 2 blocks/CU) with tile 128 wcol x 128 BATCH (grid 256, Nb=8) -> per-step
// staging traffic 128 MB vs R4/R7's 192 MB (W re-read halved). Persistence
// (R8-R13) is abandoned: every in-kernel coherence mechanism measured costs
// >= the kernel-boundary flush (grid.sync 27us; L2-nuke ~10us; uncached-H
// 28us). Epilogue T/X operands load AFTER the K-loop to keep VGPR<=128.
// ---------------------------------------------------------------------------

typedef __attribute__((ext_vector_type(8))) short bf16x8;
typedef __attribute__((ext_vector_type(4))) float f32x4;

#define GLOBAL_AS __attribute__((address_space(1)))
#define LDS_AS    __attribute__((address_space(3)))

static __device__ __forceinline__ void async_copy16(const void* g, void* l) {
    __builtin_amdgcn_global_load_lds((const GLOBAL_AS void*)g, (LDS_AS void*)l, 16, 0, 0);
}
static __device__ __forceinline__ float sigm(float x) {
    return 1.f / (1.f + __expf(-x));
}
static __device__ __forceinline__ float tanh_fast(float x) {
    return 1.f - 2.f / (__expf(2.f * x) + 1.f);
}

// ---------------- prep 1: gate table T[s][j*4+g] (embed part + bias) -------
__global__ __launch_bounds__(256) void prep_table(
    const float* __restrict__ embed,                       // [128][256]
    const float* __restrict__ wg, const float* __restrict__ wi,
    const float* __restrict__ wf, const float* __restrict__ wo,
    const float* __restrict__ bg, const float* __restrict__ bi,
    const float* __restrict__ bff, const float* __restrict__ bo,
    float* __restrict__ T)                                 // [128][4096] interleaved
{
    __shared__ float e[8][256];
    const int tid = threadIdx.x;
    const int col = blockIdx.x * 256 + tid;                // 0..4095
    const int s0 = blockIdx.y * 8;
    const int j = col >> 2, g = col & 3;
    const float* w = (g == 0 ? wg : g == 1 ? wi : g == 2 ? wf : wo) + (size_t)j * 1280;
    const float bias = (g == 0 ? bg : g == 1 ? bi : g == 2 ? bff : bo)[j];
    #pragma unroll
    for (int i = 0; i < 8; ++i) e[i][tid] = embed[(s0 + i) * 256 + tid];
    __syncthreads();
    const float4* w4 = (const float4*)w;
    float acc[8];
    #pragma unroll
    for (int i = 0; i < 8; ++i) acc[i] = bias;
    for (int d = 0; d < 64; ++d) {
        const float4 wv = w4[d];
        #pragma unroll
        for (int i = 0; i < 8; ++i) {
            const float4 ev = ((const float4*)e[i])[d];
            acc[i] += ev.x * wv.x + ev.y * wv.y + ev.z * wv.z + ev.w * wv.w;
        }
    }
    #pragma unroll
    for (int i = 0; i < 8; ++i)
        T[(size_t)(s0 + i) * 4096 + col] = acc[i];
}

// ---------------- prep 2: pack recurrent weights bf16, gate-interleaved ----
__global__ __launch_bounds__(256) void pack_w(
    const float* __restrict__ wg, const float* __restrict__ wi,
    const float* __restrict__ wf, const float* __restrict__ wo,
    __hip_bfloat16* __restrict__ Wt)                       // [4096][1024]
{
    const int col = blockIdx.x;                            // wcol = j*4+g
    const int j = col >> 2, g = col & 3;
    const float* w = (g == 0 ? wg : g == 1 ? wi : g == 2 ? wf : wo)
                     + (size_t)j * 1280 + 256;             // skip embed part
    __hip_bfloat16* out = Wt + (size_t)col * 1024;
    for (int k = threadIdx.x; k < 1024; k += 256)
        out[k] = __float2bfloat16(w[k]);
}

// ---------------- fused LSTM step ------------------------------------------
// grid 256: wcb = bid&31 (128 wcols), bb = bid>>5 (128 batch). 512 threads,
// 8 waves in 2(wm) x 4(wn); wave tile 64 wcol x 32 batch, acc[4][2].
// LDS: 2 buffers x { Ws 128x64 bf16 16KB | Hs 128x64 16KB } = 64KB ->
// 2 blocks/CU. Swizzle: 128B rows, chunk XOR (row&7) (R4/R7-proven, 0 confl).
// Schedule (R4-proven): stage(kt+1) -> vmcnt(4) [retires stage(kt)] ->
// barrier -> compute buf kt&1 -> barrier.
__global__ __launch_bounds__(512, 4) void step_fused(
    const __hip_bfloat16* __restrict__ Wt,   // [4096][1024]
    const float* __restrict__ T,             // [128][4096] interleaved
    const int* __restrict__ X,               // [1024][128]
    const __hip_bfloat16* __restrict__ Hprev,// [1024][1024]
    __hip_bfloat16* __restrict__ Hnext,      // [1024][1024]
    float* __restrict__ CSblob,              // [256*512*8] per-thread cell state
    float* __restrict__ CSout,               // [1024][1024], written at t==127
    int t)
{
    __shared__ char lds[2][32768];           // [buf]{ Ws 16KB | Hs 16KB }
    const int tid = threadIdx.x;
    const int w = tid >> 6, l = tid & 63;
    const int wm = w >> 2, wn = w & 3;
    const int wcol0 = (blockIdx.x & 31) * 128;
    const int batch0 = (blockIdx.x >> 5) * 128;

    // slot s: row = s>>3, chunk = s&7 (16B chunks of the 128B row).
    // LDS dest linear in s; global SOURCE chunk is ch^(row&7); reader applies
    // the same XOR -> involution cancels (rule 21). 4 loads per STAGE.
#define STAGE(K0, BUF) do {                                                    \
        _Pragma("unroll")                                                      \
        for (int i_ = 0; i_ < 2; ++i_) {                                       \
            const int s_ = tid + i_ * 512;                                     \
            const int r_ = s_ >> 3, c_ = s_ & 7;                               \
            const int kq_ = (K0) + ((c_ ^ (r_ & 7)) << 3);                     \
            async_copy16(Wt + (size_t)(wcol0 + r_) * 1024 + kq_,               \
                         &lds[BUF][s_ * 16]);                                  \
            async_copy16(Hprev + (size_t)(batch0 + r_) * 1024 + kq_,           \
                         &lds[BUF][16384 + s_ * 16]);                          \
        }                                                                      \
    } while (0)

    // ---- cell-state load first (retired by the prologue vmcnt(0)) ---------
    float* blob = CSblob + ((size_t)blockIdx.x * 512 + tid) * 8;
    float ap[8];
    if (t > 0) {
        f32x4 b0 = *(const f32x4*)&blob[0];
        f32x4 b1 = *(const f32x4*)&blob[4];
        #pragma unroll
        for (int c = 0; c < 4; ++c) { ap[c] = b0[c]; ap[4 + c] = b1[c]; }
    } else {
        #pragma unroll
        for (int c = 0; c < 8; ++c) ap[c] = 0.f;
    }

    // ---- prologue: tile 0 -------------------------------------------------
    STAGE(0, 0);
    asm volatile("s_waitcnt vmcnt(0)" ::: "memory");
    __builtin_amdgcn_s_barrier();

    f32x4 acc[4][2];
    const f32x4 z4 = {0.f, 0.f, 0.f, 0.f};
    #pragma unroll
    for (int m = 0; m < 4; ++m)
        #pragma unroll
        for (int n = 0; n < 2; ++n) acc[m][n] = z4;

    // ---- K loop: 16 tiles of BK=64, double-buffer, counted vmcnt ----------
    #pragma unroll
    for (int kt = 0; kt < 16; ++kt) {
        if (kt < 15) STAGE((kt + 1) * 64, (kt + 1) & 1);
        if (kt == 15)     asm volatile("s_waitcnt vmcnt(0)" ::: "memory");
        else if (kt > 0)  asm volatile("s_waitcnt vmcnt(4)" ::: "memory");
        if (kt > 0) __builtin_amdgcn_s_barrier();   // tile kt in LDS, all waves

        const char* base = &lds[kt & 1][0];
        #pragma unroll
        for (int kk = 0; kk < 2; ++kk) {
            bf16x8 af[4], bfr[2];
            #pragma unroll
            for (int m = 0; m < 4; ++m) {
                const int row = wm * 64 + m * 16 + (l & 15);
                const int ch = (kk * 4 + (l >> 4)) ^ (row & 7);
                af[m] = *(const bf16x8*)(base + (row * 8 + ch) * 16);
            }
            #pragma unroll
            for (int n = 0; n < 2; ++n) {
                const int row = wn * 32 + n * 16 + (l & 15);
                const int ch = (kk * 4 + (l >> 4)) ^ (row & 7);
                bfr[n] = *(const bf16x8*)(base + 16384 + (row * 8 + ch) * 16);
            }
            __builtin_amdgcn_s_setprio(1);
            #pragma unroll
            for (int m = 0; m < 4; ++m)
                #pragma unroll
                for (int n = 0; n < 2; ++n)
                    acc[m][n] = __builtin_amdgcn_mfma_f32_16x16x32_bf16(
                        af[m], bfr[n], acc[m][n], 0, 0, 0);
            __builtin_amdgcn_s_setprio(0);
        }
        if (kt < 15) __builtin_amdgcn_s_barrier();  // reads of this buf done
    }
#undef STAGE

    // ---- epilogue operands (post-loop: keeps K-loop VGPR low) -------------
    int batchN[2], jM[4];
    #pragma unroll
    for (int n = 0; n < 2; ++n) batchN[n] = batch0 + wn * 32 + n * 16 + (l & 15);
    #pragma unroll
    for (int m = 0; m < 4; ++m) jM[m] = (wcol0 >> 2) + wm * 16 + m * 4 + (l >> 4);

    #pragma unroll
    for (int n = 0; n < 2; ++n) {
        const int s = X[batchN[n] * 128 + t];
        const float* Ts = T + (size_t)s * 4096;
        #pragma unroll
        for (int m = 0; m < 4; ++m) {
            const f32x4 tv = *(const f32x4*)&Ts[jM[m] * 4];
            const float z0 = acc[m][n][0] + tv[0];
            const float z1 = acc[m][n][1] + tv[1];
            const float z2 = acc[m][n][2] + tv[2];
            const float z3 = acc[m][n][3] + tv[3];
            const float gg = tanh_fast(z0);
            const float ii = sigm(z1);
            const float ff = sigm(z2);
            const float oo = sigm(z3);
            const float na = gg * ii + ap[m * 2 + n] * ff;
            blob[m * 2 + n] = na;
            Hnext[(size_t)batchN[n] * 1024 + jM[m]] =
                __float2bfloat16(tanh_fast(na) * oo);
            if (t == 127)
                CSout[(size_t)batchN[n] * 1024 + jM[m]] = na;
        }
    }
}

// ---------------- final projection + softmax -------------------------------
__global__ __launch_bounds__(256) void proj_softmax(
    const float* __restrict__ A,             // [1024][1024]
    const float* __restrict__ Wp,            // [10][1024]
    const float* __restrict__ bp,            // [10]
    float* __restrict__ out)                 // [1024][10]
{
    const int row = blockIdx.x;
    const float* a = A + (size_t)row * 1024;
    float p[10];
    #pragma unroll
    for (int c = 0; c < 10; ++c) p[c] = 0.f;
    for (int k = threadIdx.x; k < 1024; k += 256) {
        const float av = a[k];
        #pragma unroll
        for (int c = 0; c < 10; ++c) p[c] += av * Wp[c * 1024 + k];
    }
    #pragma unroll
    for (int c = 0; c < 10; ++c)
        #pragma unroll
        for (int off = 32; off; off >>= 1) p[c] += __shfl_down(p[c], off);
    __shared__ float red[4][10];
    const int wv = threadIdx.x >> 6, ln = threadIdx.x & 63;
    if (ln == 0)
        for (int c = 0; c < 10; ++c) red[wv][c] = p[c];
    __syncthreads();
    if (threadIdx.x == 0) {
        float logits[10], mx = -1e30f;
        for (int c = 0; c < 10; ++c) {
            logits[c] = red[0][c] + red[1][c] + red[2][c] + red[3][c] + bp[c];
            mx = fmaxf(mx, logits[c]);
        }
        float sum = 0.f;
        for (int c = 0; c < 10; ++c) { logits[c] = __expf(logits[c] - mx); sum += logits[c]; }
        const float inv = 1.f / sum;
        for (int c = 0; c < 10; ++c) out[(size_t)row * 10 + c] = logits[c] * inv;
    }
}

// ---------------------------------------------------------------------------
extern "C" void kernel_launch(void* const* d_in, const int* in_sizes, int n_in,
                              void* d_out, int out_size, void* d_ws, size_t ws_size,
                              hipStream_t stream) {
    (void)in_sizes; (void)n_in; (void)out_size; (void)ws_size;
    const int*   x     = (const int*)d_in[0];
    const float* embed = (const float*)d_in[1];
    const float* wg    = (const float*)d_in[2];
    const float* wi    = (const float*)d_in[3];
    const float* wf    = (const float*)d_in[4];
    const float* wo    = (const float*)d_in[5];
    const float* bg    = (const float*)d_in[6];
    const float* bi    = (const float*)d_in[7];
    const float* bff   = (const float*)d_in[8];
    const float* bo    = (const float*)d_in[9];
    const float* wp    = (const float*)d_in[10];
    const float* bp    = (const float*)d_in[11];
    float* out = (float*)d_out;

    char* ws = (char*)d_ws;
    float*          T    = (float*)(ws);                        // 2 MB
    __hip_bfloat16* Wt   = (__hip_bfloat16*)(ws + (2u << 20));  // 8 MB
    __hip_bfloat16* BhA  = (__hip_bfloat16*)(ws + (10u << 20)); // 2 MB
    __hip_bfloat16* BhB  = (__hip_bfloat16*)(ws + (12u << 20)); // 2 MB
    float*          CSo  = (float*)(ws + (14u << 20));          // 4 MB
    float*          CSb  = (float*)(ws + (18u << 20));          // 4 MB

    prep_table<<<dim3(16, 16), 256, 0, stream>>>(embed, wg, wi, wf, wo, bg, bi, bff, bo, T);
    pack_w<<<4096, 256, 0, stream>>>(wg, wi, wf, wo, Wt);
    hipMemsetAsync(BhA, 0, (size_t)1024 * 1024 * sizeof(__hip_bfloat16), stream);

    for (int t = 0; t < 128; ++t) {
        const __hip_bfloat16* Hp = (t & 1) ? BhB : BhA;
        __hip_bfloat16*       Hn = (t & 1) ? BhA : BhB;
        step_fused<<<256, 512, 0, stream>>>(Wt, T, x, Hp, Hn, CSb, CSo, t);
    }
    proj_softmax<<<1024, 256, 0, stream>>>(CSo, wp, bp, out);
}